// Round 5
// baseline (92.712 us; speedup 1.0000x reference)
//
#include <hip/hip_runtime.h>
#include <math.h>

#define EPS 1e-6f

constexpr int BLOCK = 1024;     // 16 waves/block
constexpr int GRID  = 512;      // 524,288 threads total (same as before)
constexpr int NC    = 16384;    // vertices cached in LDS: 16384 * 8B = 128 KiB

typedef int      vi4 __attribute__((ext_vector_type(4)));
typedef float    vf4 __attribute__((ext_vector_type(4)));
typedef _Float16 vh4 __attribute__((ext_vector_type(4)));

// Stage 0: x [V,3] f32 -> xh [V] half4 (8B/vertex).
__global__ __launch_bounds__(256) void pad_vertices(
    const float* __restrict__ x,
    vh4* __restrict__ xh,
    int nverts)
{
    int v = blockIdx.x * 256 + threadIdx.x;
    if (v < nverts) {
        const float* p = x + 3 * v;
        vh4 t = {(_Float16)p[0], (_Float16)p[1], (_Float16)p[2], (_Float16)0.f};
        xh[v] = t;
    }
}

// Stage 1: per-block partial sums with a 128 KiB LDS cache of vertices [0, NC).
__global__ __launch_bounds__(BLOCK) void spring_energy_partial(
    const vh4*   __restrict__ xh,
    const float* __restrict__ l0,
    const float* __restrict__ k,
    const int*   __restrict__ idx,
    float* __restrict__ partials,
    int nsprings)
{
    extern __shared__ vh4 cache[];   // NC entries = 128 KiB

    // coalesced preload of the cached vertex range
    for (int i = threadIdx.x; i < NC; i += BLOCK)
        cache[i] = xh[i];
    __syncthreads();

    const int tid      = blockIdx.x * BLOCK + threadIdx.x;
    const int nthreads = GRID * BLOCK;
    const int nocts    = nsprings >> 3;   // 8 springs per iteration

    float acc = 0.f;
    for (int o = tid; o < nocts; o += nthreads) {
        const int s = o << 3;
        const vi4* ip = reinterpret_cast<const vi4*>(idx + 2 * s);
        vi4 i0 = __builtin_nontemporal_load(ip);
        vi4 i1 = __builtin_nontemporal_load(ip + 1);
        vi4 i2 = __builtin_nontemporal_load(ip + 2);
        vi4 i3 = __builtin_nontemporal_load(ip + 3);
        const vf4* lp = reinterpret_cast<const vf4*>(l0 + s);
        vf4 la = __builtin_nontemporal_load(lp);
        vf4 lb = __builtin_nontemporal_load(lp + 1);
        const vf4* kp = reinterpret_cast<const vf4*>(k + s);
        vf4 ka = __builtin_nontemporal_load(kp);
        vf4 kb = __builtin_nontemporal_load(kp + 1);

        const int ii[16] = {i0.x, i0.y, i0.z, i0.w, i1.x, i1.y, i1.z, i1.w,
                            i2.x, i2.y, i2.z, i2.w, i3.x, i3.y, i3.z, i3.w};
        vh4 P[16];
        #pragma unroll
        for (int j = 0; j < 16; ++j) {
            int v = ii[j];
            if (v < NC) P[j] = cache[v];   // LDS hit (~16% of lanes)
            else        P[j] = xh[v];      // exec-masked global gather
        }

        const float lv[8] = {la.x, la.y, la.z, la.w, lb.x, lb.y, lb.z, lb.w};
        const float kv[8] = {ka.x, ka.y, ka.z, ka.w, kb.x, kb.y, kb.z, kb.w};

        #pragma unroll
        for (int j = 0; j < 8; ++j) {
            float dx = (float)P[2*j].x - (float)P[2*j+1].x;
            float dy = (float)P[2*j].y - (float)P[2*j+1].y;
            float dz = (float)P[2*j].z - (float)P[2*j+1].z;
            float qd = dx*dx + dy*dy + dz*dz;
            float l  = sqrtf(qd + EPS);
            float dl = l - lv[j];
            acc = fmaf(kv[j] * dl, dl, acc);
        }
    }

    // scalar tail (nsprings % 8), block 0 only
    if (blockIdx.x == 0) {
        for (int s = (nocts << 3) + threadIdx.x; s < nsprings; s += BLOCK) {
            int a = idx[2 * s], b = idx[2 * s + 1];
            vh4 pa = (a < NC) ? cache[a] : xh[a];
            vh4 pb = (b < NC) ? cache[b] : xh[b];
            float dx = (float)pa.x - (float)pb.x;
            float dy = (float)pa.y - (float)pb.y;
            float dz = (float)pa.z - (float)pb.z;
            float l  = sqrtf(dx*dx + dy*dy + dz*dz + EPS);
            float dl = l - l0[s];
            acc = fmaf(k[s] * dl, dl, acc);
        }
    }

    // wave (64-lane) reduction
    #pragma unroll
    for (int off = 32; off > 0; off >>= 1)
        acc += __shfl_down(acc, off, 64);

    __shared__ float wsum[BLOCK / 64];
    const int lane = threadIdx.x & 63;
    const int wid  = threadIdx.x >> 6;
    if (lane == 0) wsum[wid] = acc;
    __syncthreads();
    if (threadIdx.x == 0) {
        float s = 0.f;
        #pragma unroll
        for (int w = 0; w < BLOCK / 64; ++w) s += wsum[w];
        partials[blockIdx.x] = s;
    }
}

// Stage 2: deterministic final reduction of GRID partials -> scalar energy.
__global__ __launch_bounds__(256) void spring_energy_final(
    const float* __restrict__ partials,
    float* __restrict__ out)
{
    float acc = 0.f;
    for (int i = threadIdx.x; i < GRID; i += 256)
        acc += partials[i];

    #pragma unroll
    for (int off = 32; off > 0; off >>= 1)
        acc += __shfl_down(acc, off, 64);

    __shared__ float wsum[4];
    const int lane = threadIdx.x & 63;
    const int wid  = threadIdx.x >> 6;
    if (lane == 0) wsum[wid] = acc;
    __syncthreads();
    if (threadIdx.x == 0)
        out[0] = 0.5f * (wsum[0] + wsum[1] + wsum[2] + wsum[3]);
}

extern "C" void kernel_launch(void* const* d_in, const int* in_sizes, int n_in,
                              void* d_out, int out_size, void* d_ws, size_t ws_size,
                              hipStream_t stream) {
    // setup_inputs() order: x [V,3] f32, l0 [E] f32, k [E] f32, indices [E,2] i32
    const float* x   = (const float*)d_in[0];
    const float* l0  = (const float*)d_in[1];
    const float* k   = (const float*)d_in[2];
    const int*   idx = (const int*)  d_in[3];
    float* out       = (float*)d_out;

    const int nverts   = in_sizes[0] / 3;   // V = 100,000
    const int nsprings = in_sizes[1];       // E = 6,400,000

    // d_ws layout: [0, nverts*8) fp16 vertices, then GRID floats of partials
    vh4*   xh       = (vh4*)d_ws;
    float* partials = (float*)((char*)d_ws + (size_t)nverts * sizeof(vh4));

    // allow 128 KiB dynamic LDS (gfx950 supports up to 160 KiB/WG)
    hipFuncSetAttribute(reinterpret_cast<const void*>(spring_energy_partial),
                        hipFuncAttributeMaxDynamicSharedMemorySize,
                        NC * (int)sizeof(vh4));

    pad_vertices<<<(nverts + 255) / 256, 256, 0, stream>>>(x, xh, nverts);
    spring_energy_partial<<<GRID, BLOCK, NC * sizeof(vh4), stream>>>(
        xh, l0, k, idx, partials, nsprings);
    spring_energy_final<<<1, 256, 0, stream>>>(partials, out);
}

// Round 6
// 76.904 us; speedup vs baseline: 1.2055x; 1.2055x over previous
//
#include <hip/hip_runtime.h>
#include <math.h>

#define EPS 1e-6f

constexpr int BLOCK = 256;
constexpr int GRID  = 2048;

typedef int   vi4 __attribute__((ext_vector_type(4)));
typedef float vf4 __attribute__((ext_vector_type(4)));

// Stage 0: pad x [V,3] -> xp [V] float4 so each vertex gather is one dwordx4.
__global__ __launch_bounds__(BLOCK) void pad_vertices(
    const float* __restrict__ x,
    vf4* __restrict__ xp,
    int nverts)
{
    int v = blockIdx.x * BLOCK + threadIdx.x;
    if (v < nverts) {
        const float* p = x + 3 * v;
        vf4 t = {p[0], p[1], p[2], 0.f};
        xp[v] = t;
    }
}

// Stage 1: per-block partial sums; gathers bypass L1 via sc0 (fetch from L2).
__global__ __launch_bounds__(BLOCK) void spring_energy_partial(
    const vf4*   __restrict__ xp,
    const float* __restrict__ l0,
    const float* __restrict__ k,
    const int*   __restrict__ idx,
    float* __restrict__ partials,
    int nsprings)
{
    const int tid      = blockIdx.x * BLOCK + threadIdx.x;
    const int nthreads = GRID * BLOCK;
    const int nquads   = nsprings >> 2;   // 4 springs per iteration

    float acc = 0.f;
    for (int q = tid; q < nquads; q += nthreads) {
        const int s = q << 2;
        vi4 ia  = __builtin_nontemporal_load(reinterpret_cast<const vi4*>(idx + 2 * s));
        vi4 ib  = __builtin_nontemporal_load(reinterpret_cast<const vi4*>(idx + 2 * s) + 1);
        vf4 l0v = __builtin_nontemporal_load(reinterpret_cast<const vf4*>(l0 + s));
        vf4 kv  = __builtin_nontemporal_load(reinterpret_cast<const vf4*>(k + s));

        const vf4* p0 = xp + ia.x;  const vf4* p1 = xp + ia.y;
        const vf4* p2 = xp + ia.z;  const vf4* p3 = xp + ia.w;
        const vf4* p4 = xp + ib.x;  const vf4* p5 = xp + ib.y;
        const vf4* p6 = xp + ib.z;  const vf4* p7 = xp + ib.w;

        vf4 a0, b0, a1, b1, a2, b2, a3, b3;
        // 8 L1-bypassing gathers issued back-to-back, one wait: 8-deep MLP.
        asm volatile(
            "global_load_dwordx4 %0, %8, off sc0\n\t"
            "global_load_dwordx4 %1, %9, off sc0\n\t"
            "global_load_dwordx4 %2, %10, off sc0\n\t"
            "global_load_dwordx4 %3, %11, off sc0\n\t"
            "global_load_dwordx4 %4, %12, off sc0\n\t"
            "global_load_dwordx4 %5, %13, off sc0\n\t"
            "global_load_dwordx4 %6, %14, off sc0\n\t"
            "global_load_dwordx4 %7, %15, off sc0\n\t"
            "s_waitcnt vmcnt(0)"
            : "=&v"(a0), "=&v"(b0), "=&v"(a1), "=&v"(b1),
              "=&v"(a2), "=&v"(b2), "=&v"(a3), "=&v"(b3)
            : "v"(p0), "v"(p1), "v"(p2), "v"(p3),
              "v"(p4), "v"(p5), "v"(p6), "v"(p7)
            : "memory");

        float dx, dy, dz, qd, l, dl;

        dx = a0.x - b0.x; dy = a0.y - b0.y; dz = a0.z - b0.z;
        qd = dx*dx + dy*dy + dz*dz;
        l  = sqrtf(qd + EPS); dl = l - l0v.x;
        acc = fmaf(kv.x * dl, dl, acc);

        dx = a1.x - b1.x; dy = a1.y - b1.y; dz = a1.z - b1.z;
        qd = dx*dx + dy*dy + dz*dz;
        l  = sqrtf(qd + EPS); dl = l - l0v.y;
        acc = fmaf(kv.y * dl, dl, acc);

        dx = a2.x - b2.x; dy = a2.y - b2.y; dz = a2.z - b2.z;
        qd = dx*dx + dy*dy + dz*dz;
        l  = sqrtf(qd + EPS); dl = l - l0v.z;
        acc = fmaf(kv.z * dl, dl, acc);

        dx = a3.x - b3.x; dy = a3.y - b3.y; dz = a3.z - b3.z;
        qd = dx*dx + dy*dy + dz*dz;
        l  = sqrtf(qd + EPS); dl = l - l0v.w;
        acc = fmaf(kv.w * dl, dl, acc);
    }

    // scalar tail (nsprings % 4), block 0 only
    if (blockIdx.x == 0) {
        for (int s = (nquads << 2) + threadIdx.x; s < nsprings; s += BLOCK) {
            int i1 = idx[2 * s], i2 = idx[2 * s + 1];
            vf4 a = xp[i1], b = xp[i2];
            float dx = a.x - b.x, dy = a.y - b.y, dz = a.z - b.z;
            float l  = sqrtf(dx*dx + dy*dy + dz*dz + EPS);
            float dl = l - l0[s];
            acc = fmaf(k[s] * dl, dl, acc);
        }
    }

    // wave (64-lane) reduction
    #pragma unroll
    for (int off = 32; off > 0; off >>= 1)
        acc += __shfl_down(acc, off, 64);

    __shared__ float wsum[BLOCK / 64];
    const int lane = threadIdx.x & 63;
    const int wid  = threadIdx.x >> 6;
    if (lane == 0) wsum[wid] = acc;
    __syncthreads();
    if (threadIdx.x == 0)
        partials[blockIdx.x] = wsum[0] + wsum[1] + wsum[2] + wsum[3];
}

// Stage 2: deterministic final reduction of GRID partials -> scalar energy.
__global__ __launch_bounds__(BLOCK) void spring_energy_final(
    const float* __restrict__ partials,
    float* __restrict__ out)
{
    float acc = 0.f;
    for (int i = threadIdx.x; i < GRID; i += BLOCK)
        acc += partials[i];

    #pragma unroll
    for (int off = 32; off > 0; off >>= 1)
        acc += __shfl_down(acc, off, 64);

    __shared__ float wsum[BLOCK / 64];
    const int lane = threadIdx.x & 63;
    const int wid  = threadIdx.x >> 6;
    if (lane == 0) wsum[wid] = acc;
    __syncthreads();
    if (threadIdx.x == 0)
        out[0] = 0.5f * (wsum[0] + wsum[1] + wsum[2] + wsum[3]);
}

extern "C" void kernel_launch(void* const* d_in, const int* in_sizes, int n_in,
                              void* d_out, int out_size, void* d_ws, size_t ws_size,
                              hipStream_t stream) {
    // setup_inputs() order: x [V,3] f32, l0 [E] f32, k [E] f32, indices [E,2] i32
    const float* x   = (const float*)d_in[0];
    const float* l0  = (const float*)d_in[1];
    const float* k   = (const float*)d_in[2];
    const int*   idx = (const int*)  d_in[3];
    float* out       = (float*)d_out;

    const int nverts   = in_sizes[0] / 3;   // V = 100,000
    const int nsprings = in_sizes[1];       // E = 6,400,000

    // d_ws layout: [0, nverts*16) padded vertices, then GRID floats of partials
    vf4*   xp       = (vf4*)d_ws;
    float* partials = (float*)((char*)d_ws + (size_t)nverts * sizeof(vf4));

    pad_vertices<<<(nverts + BLOCK - 1) / BLOCK, BLOCK, 0, stream>>>(x, xp, nverts);
    spring_energy_partial<<<GRID, BLOCK, 0, stream>>>(xp, l0, k, idx, partials, nsprings);
    spring_energy_final<<<1, BLOCK, 0, stream>>>(partials, out);
}